// Round 15
// baseline (152.518 us; speedup 1.0000x reference)
//
#include <hip/hip_runtime.h>
#include <math.h>

typedef __bf16 bf16;
typedef __bf16 bf16x4 __attribute__((ext_vector_type(4)));
typedef __bf16 bf16x8 __attribute__((ext_vector_type(8)));
typedef float f32x4 __attribute__((ext_vector_type(4)));
typedef unsigned short u16;
typedef unsigned short u16x8 __attribute__((ext_vector_type(8)));
typedef unsigned int u32;

__device__ __forceinline__ u16 f2bf(float f) {
  union { float f; u32 u; } v; v.f = f;
  u32 u = v.u;
  return (u16)((u + 0x7FFFu + ((u >> 16) & 1u)) >> 16);
}
__device__ __forceinline__ float bf2f(u16 u) {
  union { u32 u; float f; } v; v.u = (u32)u << 16;
  return v.f;
}

__device__ __forceinline__ f32x4 mfma16(bf16x8 a, bf16x8 b, f32x4 c) {
  return __builtin_amdgcn_mfma_f32_16x16x32_bf16(a, b, c, 0, 0, 0);
}

// MFMA-fragment-packed layout for a [R][C] bf16 matrix (16x32 fragments):
//   addr(r,c) = ((r>>4)*(C>>5) + (c>>5))*512 + ((c>>3)&3)*128 + (r&15)*8 + (c&7)
// Consumer: lane l reads 16B at fragbase + l*16 -> one coalesced 1-KB dwordx4.
__device__ __forceinline__ size_t pk_addr(int r, int c, int C) {
  return ((size_t)(r >> 4) * (C >> 5) + (c >> 5)) * 512 +
         ((c >> 3) & 3) * 128 + (r & 15) * 8 + (c & 7);
}

// ---------------- weight fp32 -> bf16 frag-packed transpose ------------------
__device__ __forceinline__ void wconv_body(const float* __restrict__ W,
                                           u16* __restrict__ Wt, int K, int N,
                                           int bx, int by) {
  __shared__ float tile[64][65];
  const int k0 = by * 64, n0 = bx * 64;
  const int t = threadIdx.x;
  const int tr = t >> 4;
  const int tc = (t & 15) * 4;
#pragma unroll
  for (int it = 0; it < 4; it++) {
    const int r = tr + it * 16;
    const float4 v = *(const float4*)(W + (size_t)(k0 + r) * N + n0 + tc);
    tile[r][tc] = v.x; tile[r][tc + 1] = v.y; tile[r][tc + 2] = v.z; tile[r][tc + 3] = v.w;
  }
  __syncthreads();
#pragma unroll
  for (int it = 0; it < 4; it++) {
    const int rn = tr + it * 16;
    const int n = n0 + rn;
    const int k = k0 + tc;
    ushort4 o;
    o.x = f2bf(tile[tc][rn]);
    o.y = f2bf(tile[tc + 1][rn]);
    o.z = f2bf(tile[tc + 2][rn]);
    o.w = f2bf(tile[tc + 3][rn]);
    *(ushort4*)(Wt + pk_addr(n, k, K)) = o;
  }
}

// ---------------- LayerNorm body (fp32 in -> frag-packed bf16 out) -----------
__device__ __forceinline__ void ln_body(const float* __restrict__ x,
                                        const float* __restrict__ w,
                                        const float* __restrict__ b,
                                        u16* __restrict__ out, int row) {
  const int t = threadIdx.x;
  const float4 v = *(const float4*)(x + (size_t)row * 1024 + t * 4);
  float s = v.x + v.y + v.z + v.w;
  float s2 = v.x * v.x + v.y * v.y + v.z * v.z + v.w * v.w;
#pragma unroll
  for (int m = 1; m < 64; m <<= 1) {
    s += __shfl_xor(s, m);
    s2 += __shfl_xor(s2, m);
  }
  __shared__ float red[8];
  if ((t & 63) == 0) { red[t >> 6] = s; red[4 + (t >> 6)] = s2; }
  __syncthreads();
  s = red[0] + red[1] + red[2] + red[3];
  s2 = red[4] + red[5] + red[6] + red[7];
  const float mu = s * (1.f / 1024.f);
  const float var = fmaxf(s2 * (1.f / 1024.f) - mu * mu, 0.f);
  const float rstd = rsqrtf(var + 1e-5f);
  const float* wp = w + t * 4;
  const float* bp = b + t * 4;
  ushort4 o;
  o.x = f2bf((v.x - mu) * rstd * wp[0] + bp[0]);
  o.y = f2bf((v.y - mu) * rstd * wp[1] + bp[1]);
  o.z = f2bf((v.z - mu) * rstd * wp[2] + bp[2]);
  o.w = f2bf((v.w - mu) * rstd * wp[3] + bp[3]);
  *(ushort4*)(out + pk_addr(row, t * 4, 1024)) = o;
}

// ---------------- fused prep: all weight conversions + first LN --------------
__global__ __launch_bounds__(256)
void prep_all(const float* __restrict__ Wqkv, const float* __restrict__ Wo,
              const float* __restrict__ W1, const float* __restrict__ W2,
              const float* __restrict__ x, const float* __restrict__ ln_aw,
              const float* __restrict__ ln_ab,
              u16* __restrict__ Wqkv_t, u16* __restrict__ Wo_t,
              u16* __restrict__ W1_t, u16* __restrict__ W2_t,
              u16* __restrict__ h1) {
  const int id = blockIdx.x;  // uniform per block
  if (id < 768)       { wconv_body(Wqkv, Wqkv_t, 1024, 3072, id % 48, id / 48); }
  else if (id < 1024) { const int j = id - 768;  wconv_body(Wo, Wo_t, 1024, 1024, j % 16, j / 16); }
  else if (id < 2048) { const int j = id - 1024; wconv_body(W1, W1_t, 1024, 4096, j % 64, j / 64); }
  else if (id < 3072) { const int j = id - 2048; wconv_body(W2, W2_t, 4096, 1024, j % 16, j / 16); }
  else                { ln_body(x, ln_aw, ln_ab, h1, id - 3072); }
}

// ---------------- fused: x2 = x + sum(pb[0..3]); h2 = LN(x2) packed ----------
__global__ __launch_bounds__(256)
void reduce_ln(const float* __restrict__ x, const u16* __restrict__ pb,
               const float* __restrict__ w, const float* __restrict__ b,
               float* __restrict__ x2, u16* __restrict__ h2) {
  const int row = blockIdx.x;
  const int t = threadIdx.x;
  const size_t base = (size_t)row * 1024 + t * 4;
  float4 v = *(const float4*)(x + base);
#pragma unroll
  for (int z = 0; z < 4; z++) {
    const ushort4 p = *(const ushort4*)(pb + (size_t)z * 2097152 + base);
    v.x += bf2f(p.x); v.y += bf2f(p.y); v.z += bf2f(p.z); v.w += bf2f(p.w);
  }
  *(float4*)(x2 + base) = v;
  float s = v.x + v.y + v.z + v.w;
  float s2 = v.x * v.x + v.y * v.y + v.z * v.z + v.w * v.w;
#pragma unroll
  for (int m = 1; m < 64; m <<= 1) {
    s += __shfl_xor(s, m);
    s2 += __shfl_xor(s2, m);
  }
  __shared__ float red[8];
  if ((t & 63) == 0) { red[t >> 6] = s; red[4 + (t >> 6)] = s2; }
  __syncthreads();
  s = red[0] + red[1] + red[2] + red[3];
  s2 = red[4] + red[5] + red[6] + red[7];
  const float mu = s * (1.f / 1024.f);
  const float var = fmaxf(s2 * (1.f / 1024.f) - mu * mu, 0.f);
  const float rstd = rsqrtf(var + 1e-5f);
  const float* wp = w + t * 4;
  const float* bp = b + t * 4;
  ushort4 o;
  o.x = f2bf((v.x - mu) * rstd * wp[0] + bp[0]);
  o.y = f2bf((v.y - mu) * rstd * wp[1] + bp[1]);
  o.z = f2bf((v.z - mu) * rstd * wp[2] + bp[2]);
  o.w = f2bf((v.w - mu) * rstd * wp[3] + bp[3]);
  *(ushort4*)(h2 + pk_addr(row, t * 4, 1024)) = o;
}

// ---------------- fused: out = x2 + bias + sum(pb[0..3]) ---------------------
__global__ __launch_bounds__(256)
void reduce_out(const float* __restrict__ x2, const float* __restrict__ bias,
                const u16* __restrict__ pb, float* __restrict__ out) {
  const size_t base = ((size_t)blockIdx.x * 256 + threadIdx.x) * 4;
  const int col = (int)(base & 1023);
  float4 v = *(const float4*)(x2 + base);
  const float4 bb = *(const float4*)(bias + col);
  v.x += bb.x; v.y += bb.y; v.z += bb.z; v.w += bb.w;
#pragma unroll
  for (int z = 0; z < 4; z++) {
    const ushort4 p = *(const ushort4*)(pb + (size_t)z * 2097152 + base);
    v.x += bf2f(p.x); v.y += bf2f(p.y); v.z += bf2f(p.z); v.w += bf2f(p.w);
  }
  *(float4*)(out + base) = v;
}

// ---------------- LDS-free frag-packed bf16 GEMM, 128x128, split-K ----------
// (round-12 best config: depth-1 dbuf, launch_bounds(256,3))
template <int EPI, int KS>
__global__ __launch_bounds__(256, 3)
void gemm_pk(const u16* __restrict__ Ap, const u16* __restrict__ Bp,
             int M, int N, int K,
             const float* __restrict__ bias, u16* __restrict__ pb,
             u16* __restrict__ outB,
             u16* __restrict__ qo, u16* __restrict__ ko, u16* __restrict__ vo) {
  const int t = threadIdx.x;
  const int l = t & 63;
  const int w = t >> 6;
  const int WR = (w >> 1) * 64, WC = (w & 1) * 64;
  const int l15 = l & 15, lg = l >> 4;

  // XCD-chunked swizzle (gridDim.x % 8 == 0 at all call sites)
  const int nx = gridDim.x;
  const u32 bid = blockIdx.y * nx + blockIdx.x;
  const int nxc = nx >> 3;
  const u32 r = bid >> 3;
  const int bx = (bid & 7) * nxc + (int)(r % (u32)nxc);
  const int by = (int)(r / (u32)nxc);

  const int m0 = by * 128, n0 = bx * 128;
  const int KT = K >> 5;               // total k-tiles
  const int nt = (K / KS) >> 5;        // k-tiles this z-slice
  const int t0 = blockIdx.z * nt;

  const u16* aB = Ap + ((size_t)((m0 + WR) >> 4) * KT + t0) * 512 + l * 8;
  const u16* bB = Bp + ((size_t)((n0 + WC) >> 4) * KT + t0) * 512 + l * 8;

  f32x4 acc[4][4] = {};
  bf16x8 a0[4], b0[4], a1[4], b1[4];

  auto LD = [&](bf16x8 (&af)[4], bf16x8 (&bf_)[4], int ti) {
#pragma unroll
    for (int i = 0; i < 4; i++)
      af[i] = *(const bf16x8*)(aB + ((size_t)i * KT + ti) * 512);
#pragma unroll
    for (int j = 0; j < 4; j++)
      bf_[j] = *(const bf16x8*)(bB + ((size_t)j * KT + ti) * 512);
  };
  auto FMA = [&](bf16x8 (&af)[4], bf16x8 (&bf_)[4]) {
    __builtin_amdgcn_s_setprio(1);
#pragma unroll
    for (int i = 0; i < 4; i++)
#pragma unroll
      for (int j = 0; j < 4; j++)
        acc[i][j] = mfma16(af[i], bf_[j], acc[i][j]);
    __builtin_amdgcn_s_setprio(0);
  };

  LD(a0, b0, 0);
  for (int ti = 0; ti < nt; ti += 2) {
    LD(a1, b1, (ti + 1 < nt) ? ti + 1 : ti);   // prefetch; clamped tail reload
    FMA(a0, b0);
    LD(a0, b0, (ti + 2 < nt) ? ti + 2 : ti);
    FMA(a1, b1);
  }

  const int mr0 = m0 + WR + lg * 4;
  const int nc0 = n0 + WC + l15;
#pragma unroll
  for (int i = 0; i < 4; i++) {
    const int mr = mr0 + i * 16;  // base row (multiple of 4); rows mr..mr+3
#pragma unroll
    for (int j = 0; j < 4; j++) {
      const int nc = nc0 + j * 16;
      if (EPI == 0) {
        const int sel = nc >> 10;
        const int d = nc & 1023;
        const int h = d >> 6, dl = d & 63;
        const int kt2 = mr >> 5;
        if (sel == 2) {
          // Vp[h][kt][nb][lane][el] (attn layout)
          const int lgp = (mr >> 3) & 3, el0 = mr & 7;
          const int nb = dl >> 4, l15p = dl & 15;
          u16* dst = vo + (size_t)(h * 64 + kt2) * 2048 + nb * 512 +
                     (lgp * 16 + l15p) * 8 + el0;
          ushort4 o;
          o.x = f2bf(acc[i][j][0]); o.y = f2bf(acc[i][j][1]);
          o.z = f2bf(acc[i][j][2]); o.w = f2bf(acc[i][j][3]);
          *(ushort4*)dst = o;
        } else {
          // Qp/Kp[h][kt][f][kk][lane][el] (attn layout)
          const int f = (mr >> 4) & 1, l15p0 = mr & 15;
          const int kk = dl >> 5, lgp = (dl >> 3) & 3, el = dl & 7;
          u16* dst = (sel == 0 ? qo : ko) + (size_t)(h * 64 + kt2) * 2048 +
                     f * 1024 + kk * 512 + (lgp * 16 + l15p0) * 8 + el;
#pragma unroll
          for (int e = 0; e < 4; e++)
            dst[e * 8] = f2bf(acc[i][j][e]);
        }
      } else if (EPI == 2) {
        const float bb = bias[nc];
#pragma unroll
        for (int e = 0; e < 4; e++) {
          const float v = acc[i][j][e] + bb;
          const float g = 0.5f * v * (1.0f + tanhf(0.7978845608028654f * (v + 0.044715f * v * v * v)));
          outB[pk_addr(mr + e, nc, 4096)] = f2bf(g);
        }
      } else {
        u16* po = pb + (size_t)blockIdx.z * M * N;
#pragma unroll
        for (int e = 0; e < 4; e++)
          po[(size_t)(mr + e) * N + nc] = f2bf(acc[i][j][e]);
      }
    }
  }
}

// ---------------- causal flash attention v4b: bf16 LDS partials --------------
// Combine buffer shrunk f32->bf16: smem 33280->20480 B. VGPR (88) now binds
// occupancy at 5 blocks/CU (was LDS-bound at 4) and combine LDS reads halve.
__device__ __forceinline__ void attn_load(
    bf16x8 (&kf)[2][2], bf16x8 (&vf)[4],
    const u16* __restrict__ Kp, const u16* __restrict__ Vp,
    int hkt, int l) {  // hkt = (h*64 + kt) * 2048
#pragma unroll
  for (int f = 0; f < 2; f++)
#pragma unroll
    for (int kk = 0; kk < 2; kk++)
      kf[kk][f] = *(const bf16x8*)(Kp + hkt + f * 1024 + kk * 512 + l * 8);
#pragma unroll
  for (int nb = 0; nb < 4; nb++)
    vf[nb] = *(const bf16x8*)(Vp + hkt + nb * 512 + l * 8);
}

__device__ __forceinline__ void attn_tile(
    const bf16x8 (&kf)[2][2], const bf16x8 (&vf)[4], const bf16x8 (&qf)[2][2],
    f32x4 (&accO)[2][4], float (&lsum)[2], u16* myP,
    int k0, bool diag, int qb, int l15, int lg) {
  f32x4 sv[2][2] = {};
  __builtin_amdgcn_s_setprio(1);
#pragma unroll
  for (int g = 0; g < 2; g++)
#pragma unroll
    for (int f = 0; f < 2; f++)
#pragma unroll
      for (int kk = 0; kk < 2; kk++)
        sv[g][f] = mfma16(kf[kk][f], qf[g][kk], sv[g][f]);
  __builtin_amdgcn_s_setprio(0);
#pragma unroll
  for (int g = 0; g < 2; g++) {
#pragma unroll
    for (int f = 0; f < 2; f++) {
      bf16x4 pk;
      float ps = 0.f;
#pragma unroll
      for (int e = 0; e < 4; e++) {
        float p = exp2f(sv[g][f][e] * 0.1803368801f);  // exp(s/8)
        if (diag && (k0 + f * 16 + lg * 4 + e > qb + g * 16 + l15)) p = 0.f;
        ps += p;
        pk[e] = (bf16)p;
      }
      lsum[g] += ps;
      *(bf16x4*)(myP + g * 640 + l15 * 40 + f * 16 + lg * 4) = pk;
    }
  }
  const bf16x8 pf0 = *(const bf16x8*)(myP + l15 * 40 + lg * 8);
  const bf16x8 pf1 = *(const bf16x8*)(myP + 640 + l15 * 40 + lg * 8);
  __builtin_amdgcn_s_setprio(1);
#pragma unroll
  for (int nb = 0; nb < 4; nb++) {
    accO[0][nb] = mfma16(pf0, vf[nb], accO[0][nb]);
    accO[1][nb] = mfma16(pf1, vf[nb], accO[1][nb]);
  }
  __builtin_amdgcn_s_setprio(0);
}

__global__ __launch_bounds__(256)
void attn_fwd(const u16* __restrict__ Qp, const u16* __restrict__ Kp,
              const u16* __restrict__ Vp, u16* __restrict__ Ob) {
  __shared__ __attribute__((aligned(16))) char smem[20480];
  u16* sOb = (u16*)smem;               // [4][2048] bf16 (after barrier)
  float* sL = (float*)(smem + 16384);  // [4][32]
  u16* lP = (u16*)smem;                // [2 buf][4 waves][1280 u16] (pre-barrier)

  const int t = threadIdx.x;
  const int l = t & 63, w = t >> 6;
  const int l15 = l & 15, lg = l >> 4;
  const u32 bid = blockIdx.x;
  const u32 vb = (bid & 7) * 128 + (bid >> 3);
  const int h = (int)(vb >> 6);
  const int qt = 63 - (int)(vb & 63);  // LPT within chunk
  const int qb = qt * 32;

  u16* myPA = lP + w * 1280;
  u16* myPB = lP + 5120 + w * 1280;

  bf16x8 qf[2][2];
#pragma unroll
  for (int g = 0; g < 2; g++)
#pragma unroll
    for (int kk = 0; kk < 2; kk++)
      qf[g][kk] = *(const bf16x8*)(Qp + (size_t)(h * 64 + qt) * 2048 +
                                   g * 1024 + kk * 512 + l * 8);

  f32x4 accO[2][4] = {};
  float lsum[2] = {0.f, 0.f};

  if (w <= qt) {
    const int hb = h * 64;
    bf16x8 kfA[2][2], vfA[4], kfB[2][2], vfB[4];
    attn_load(kfA, vfA, Kp, Vp, (hb + w) * 2048, l);
    int kt = w;
    while (true) {
      const int ktB = kt + 4;
      const bool hasB = (ktB <= qt);
      attn_load(kfB, vfB, Kp, Vp, (hb + (hasB ? ktB : kt)) * 2048, l);
      attn_tile(kfA, vfA, qf, accO, lsum, myPA, kt * 32, kt == qt, qb, l15, lg);
      if (!hasB) break;
      const int ktA = kt + 8;
      const bool hasA = (ktA <= qt);
      attn_load(kfA, vfA, Kp, Vp, (hb + (hasA ? ktA : ktB)) * 2048, l);
      attn_tile(kfB, vfB, qf, accO, lsum, myPB, ktB * 32, ktB == qt, qb, l15, lg);
      if (!hasA) break;
      kt = ktA;
    }
  }

  float lsr[2];
#pragma unroll
  for (int g = 0; g < 2; g++) {
    float v = lsum[g];
    v += __shfl_xor(v, 16);
    v += __shfl_xor(v, 32);
    lsr[g] = v;
  }

  __syncthreads();  // all waves done with lP; smem becomes sOb
#pragma unroll
  for (int g = 0; g < 2; g++) {
#pragma unroll
    for (int nb = 0; nb < 4; nb++)
#pragma unroll
      for (int e = 0; e < 4; e++)
        sOb[w * 2048 + (g * 16 + lg * 4 + e) * 64 + nb * 16 + l15] =
            f2bf(accO[g][nb][e]);
    if (lg == 0) sL[w * 32 + g * 16 + l15] = lsr[g];
  }
  __syncthreads();

  const int base = t * 8;
  const int row = base >> 6;
  const int col = base & 63;
  float a[8] = {};
  float ls = 0.f;
#pragma unroll
  for (int ww = 0; ww < 4; ww++) {
    const u16x8 pv = *(const u16x8*)&sOb[ww * 2048 + base];
#pragma unroll
    for (int j = 0; j < 8; j++) a[j] += bf2f(pv[j]);
    ls += sL[ww * 32 + row];
  }
  const float rinv = 1.0f / ls;
  u16x8 o;
#pragma unroll
  for (int j = 0; j < 8; j++) o[j] = f2bf(a[j] * rinv);
  const int grow = qb + row;
  const int gcol = h * 64 + col;
  *(u16x8*)(Ob + pk_addr(grow, gcol, 1024)) = o;
}

// ---------------- launch ----------------------------------------------------
extern "C" void kernel_launch(void* const* d_in, const int* in_sizes, int n_in,
                              void* d_out, int out_size, void* d_ws, size_t ws_size,
                              hipStream_t stream) {
  const float* x     = (const float*)d_in[0];
  const float* W_qkv = (const float*)d_in[1];
  const float* W_o   = (const float*)d_in[2];
  const float* W1    = (const float*)d_in[3];
  const float* b1    = (const float*)d_in[4];
  const float* W2    = (const float*)d_in[5];
  const float* b2    = (const float*)d_in[6];
  const float* ln_aw = (const float*)d_in[7];
  const float* ln_ab = (const float*)d_in[8];
  const float* ln_mw = (const float*)d_in[9];
  const float* ln_mb = (const float*)d_in[10];

  // workspace (peak 71.3 MB):
  char* ws = (char*)d_ws;
  u16* Wqkv_t = (u16*)(ws);                  // pk [3072][1024]     6 MB persistent
  u16* Wo_t   = (u16*)(ws + 6291456);        // pk [1024][1024]     2 MB persistent
  u16* W1_t   = (u16*)(ws + 8388608);        // pk [4096][1024]     8 MB persistent
  u16* W2_t   = (u16*)(ws + 16777216);       // pk [1024][4096]     8 MB persistent
  u16* h1     = (u16*)(ws + 25165824);       // pk [2048][1024]     4 MB (h2 alias)
  u16* h2     = h1;
  u16* Qp     = (u16*)(ws + 29360128);       // attn-packed Q       4 MB
  u16* Kp     = (u16*)(ws + 33554432);       // attn-packed K       4 MB
  u16* Vp     = (u16*)(ws + 37748736);       // attn-packed V       4 MB
  u16* attnb  = (u16*)(ws + 41943040);       // pk [2048][1024]     4 MB
  u16* ffb    = (u16*)(ws + 29360128);       // pk [2048][4096]    16 MB aliases Qp..attnb
  u16* pb     = (u16*)(ws + 46137344);       // 4x bf16 [2048][1024] 16 MB partials
  float* x2   = (float*)(ws + 62914560);     // f32 [2048][1024]    8 MB
  (void)ws_size; (void)in_sizes; (void)n_in; (void)out_size;

  // weights conversion + first LN fused (independent work, one launch)
  prep_all<<<5120, 256, 0, stream>>>(W_qkv, W_o, W1, W2, x, ln_aw, ln_ab,
                                     Wqkv_t, Wo_t, W1_t, W2_t, h1);

  // QKV: M=2048 N=3072 K=1024 -> (24,16) = 384 blocks
  gemm_pk<0, 1><<<dim3(24, 16), 256, 0, stream>>>(
      h1, Wqkv_t, 2048, 3072, 1024, nullptr, nullptr, nullptr, Qp, Kp, Vp);

  attn_fwd<<<1024, 256, 0, stream>>>(Qp, Kp, Vp, attnb);

  // W_o: M=2048 N=1024 K=1024, split-K=4 -> (8,16,4) = 512 blocks
  gemm_pk<4, 4><<<dim3(8, 16, 4), 256, 0, stream>>>(
      attnb, Wo_t, 2048, 1024, 1024, nullptr, pb, nullptr, nullptr, nullptr, nullptr);

  reduce_ln<<<2048, 256, 0, stream>>>(x, pb, ln_mw, ln_mb, x2, h2);

  // FF1: M=2048 N=4096 K=1024 -> (32,16) = 512 blocks
  gemm_pk<2, 1><<<dim3(32, 16), 256, 0, stream>>>(
      h2, W1_t, 2048, 4096, 1024, b1, nullptr, ffb, nullptr, nullptr, nullptr);

  // FF2: M=2048 N=1024 K=4096, split-K=4 -> (8,16,4) = 512 blocks
  gemm_pk<4, 4><<<dim3(8, 16, 4), 256, 0, stream>>>(
      ffb, W2_t, 2048, 1024, 4096, nullptr, pb, nullptr, nullptr, nullptr, nullptr);

  reduce_out<<<2048, 256, 0, stream>>>(x2, b2, pb, (float*)d_out);
}

// Round 16
// 148.366 us; speedup vs baseline: 1.0280x; 1.0280x over previous
//
#include <hip/hip_runtime.h>
#include <math.h>

typedef __bf16 bf16;
typedef __bf16 bf16x4 __attribute__((ext_vector_type(4)));
typedef __bf16 bf16x8 __attribute__((ext_vector_type(8)));
typedef float f32x4 __attribute__((ext_vector_type(4)));
typedef unsigned short u16;
typedef unsigned short u16x8 __attribute__((ext_vector_type(8)));
typedef unsigned int u32;

__device__ __forceinline__ u16 f2bf(float f) {
  union { float f; u32 u; } v; v.f = f;
  u32 u = v.u;
  return (u16)((u + 0x7FFFu + ((u >> 16) & 1u)) >> 16);
}
__device__ __forceinline__ float bf2f(u16 u) {
  union { u32 u; float f; } v; v.u = (u32)u << 16;
  return v.f;
}

__device__ __forceinline__ f32x4 mfma16(bf16x8 a, bf16x8 b, f32x4 c) {
  return __builtin_amdgcn_mfma_f32_16x16x32_bf16(a, b, c, 0, 0, 0);
}

// MFMA-fragment-packed layout for a [R][C] bf16 matrix (16x32 fragments):
//   addr(r,c) = ((r>>4)*(C>>5) + (c>>5))*512 + ((c>>3)&3)*128 + (r&15)*8 + (c&7)
// Consumer: lane l reads 16B at fragbase + l*16 -> one coalesced 1-KB dwordx4.
__device__ __forceinline__ size_t pk_addr(int r, int c, int C) {
  return ((size_t)(r >> 4) * (C >> 5) + (c >> 5)) * 512 +
         ((c >> 3) & 3) * 128 + (r & 15) * 8 + (c & 7);
}

// ---------------- weight fp32 -> bf16 frag-packed transpose ------------------
__device__ __forceinline__ void wconv_body(const float* __restrict__ W,
                                           u16* __restrict__ Wt, int K, int N,
                                           int bx, int by) {
  __shared__ float tile[64][65];
  const int k0 = by * 64, n0 = bx * 64;
  const int t = threadIdx.x;
  const int tr = t >> 4;
  const int tc = (t & 15) * 4;
#pragma unroll
  for (int it = 0; it < 4; it++) {
    const int r = tr + it * 16;
    const float4 v = *(const float4*)(W + (size_t)(k0 + r) * N + n0 + tc);
    tile[r][tc] = v.x; tile[r][tc + 1] = v.y; tile[r][tc + 2] = v.z; tile[r][tc + 3] = v.w;
  }
  __syncthreads();
#pragma unroll
  for (int it = 0; it < 4; it++) {
    const int rn = tr + it * 16;
    const int n = n0 + rn;
    const int k = k0 + tc;
    ushort4 o;
    o.x = f2bf(tile[tc][rn]);
    o.y = f2bf(tile[tc + 1][rn]);
    o.z = f2bf(tile[tc + 2][rn]);
    o.w = f2bf(tile[tc + 3][rn]);
    *(ushort4*)(Wt + pk_addr(n, k, K)) = o;
  }
}

// ---------------- LayerNorm body (fp32 in -> frag-packed bf16 out) -----------
__device__ __forceinline__ void ln_body(const float* __restrict__ x,
                                        const float* __restrict__ w,
                                        const float* __restrict__ b,
                                        u16* __restrict__ out, int row) {
  const int t = threadIdx.x;
  const float4 v = *(const float4*)(x + (size_t)row * 1024 + t * 4);
  float s = v.x + v.y + v.z + v.w;
  float s2 = v.x * v.x + v.y * v.y + v.z * v.z + v.w * v.w;
#pragma unroll
  for (int m = 1; m < 64; m <<= 1) {
    s += __shfl_xor(s, m);
    s2 += __shfl_xor(s2, m);
  }
  __shared__ float red[8];
  if ((t & 63) == 0) { red[t >> 6] = s; red[4 + (t >> 6)] = s2; }
  __syncthreads();
  s = red[0] + red[1] + red[2] + red[3];
  s2 = red[4] + red[5] + red[6] + red[7];
  const float mu = s * (1.f / 1024.f);
  const float var = fmaxf(s2 * (1.f / 1024.f) - mu * mu, 0.f);
  const float rstd = rsqrtf(var + 1e-5f);
  const float* wp = w + t * 4;
  const float* bp = b + t * 4;
  ushort4 o;
  o.x = f2bf((v.x - mu) * rstd * wp[0] + bp[0]);
  o.y = f2bf((v.y - mu) * rstd * wp[1] + bp[1]);
  o.z = f2bf((v.z - mu) * rstd * wp[2] + bp[2]);
  o.w = f2bf((v.w - mu) * rstd * wp[3] + bp[3]);
  *(ushort4*)(out + pk_addr(row, t * 4, 1024)) = o;
}

// ---------------- fused prep: all weight conversions + first LN --------------
__global__ __launch_bounds__(256)
void prep_all(const float* __restrict__ Wqkv, const float* __restrict__ Wo,
              const float* __restrict__ W1, const float* __restrict__ W2,
              const float* __restrict__ x, const float* __restrict__ ln_aw,
              const float* __restrict__ ln_ab,
              u16* __restrict__ Wqkv_t, u16* __restrict__ Wo_t,
              u16* __restrict__ W1_t, u16* __restrict__ W2_t,
              u16* __restrict__ h1) {
  const int id = blockIdx.x;  // uniform per block
  if (id < 768)       { wconv_body(Wqkv, Wqkv_t, 1024, 3072, id % 48, id / 48); }
  else if (id < 1024) { const int j = id - 768;  wconv_body(Wo, Wo_t, 1024, 1024, j % 16, j / 16); }
  else if (id < 2048) { const int j = id - 1024; wconv_body(W1, W1_t, 1024, 4096, j % 64, j / 64); }
  else if (id < 3072) { const int j = id - 2048; wconv_body(W2, W2_t, 4096, 1024, j % 16, j / 16); }
  else                { ln_body(x, ln_aw, ln_ab, h1, id - 3072); }
}

// ---------------- fused: x2 = x + sum(pb[0..3]); h2 = LN(x2) packed ----------
__global__ __launch_bounds__(256)
void reduce_ln(const float* __restrict__ x, const u16* __restrict__ pb,
               const float* __restrict__ w, const float* __restrict__ b,
               float* __restrict__ x2, u16* __restrict__ h2) {
  const int row = blockIdx.x;
  const int t = threadIdx.x;
  const size_t base = (size_t)row * 1024 + t * 4;
  float4 v = *(const float4*)(x + base);
#pragma unroll
  for (int z = 0; z < 4; z++) {
    const ushort4 p = *(const ushort4*)(pb + (size_t)z * 2097152 + base);
    v.x += bf2f(p.x); v.y += bf2f(p.y); v.z += bf2f(p.z); v.w += bf2f(p.w);
  }
  *(float4*)(x2 + base) = v;
  float s = v.x + v.y + v.z + v.w;
  float s2 = v.x * v.x + v.y * v.y + v.z * v.z + v.w * v.w;
#pragma unroll
  for (int m = 1; m < 64; m <<= 1) {
    s += __shfl_xor(s, m);
    s2 += __shfl_xor(s2, m);
  }
  __shared__ float red[8];
  if ((t & 63) == 0) { red[t >> 6] = s; red[4 + (t >> 6)] = s2; }
  __syncthreads();
  s = red[0] + red[1] + red[2] + red[3];
  s2 = red[4] + red[5] + red[6] + red[7];
  const float mu = s * (1.f / 1024.f);
  const float var = fmaxf(s2 * (1.f / 1024.f) - mu * mu, 0.f);
  const float rstd = rsqrtf(var + 1e-5f);
  const float* wp = w + t * 4;
  const float* bp = b + t * 4;
  ushort4 o;
  o.x = f2bf((v.x - mu) * rstd * wp[0] + bp[0]);
  o.y = f2bf((v.y - mu) * rstd * wp[1] + bp[1]);
  o.z = f2bf((v.z - mu) * rstd * wp[2] + bp[2]);
  o.w = f2bf((v.w - mu) * rstd * wp[3] + bp[3]);
  *(ushort4*)(h2 + pk_addr(row, t * 4, 1024)) = o;
}

// ---------------- fused: out = x2 + bias + sum(pb[0..3]) ---------------------
__global__ __launch_bounds__(256)
void reduce_out(const float* __restrict__ x2, const float* __restrict__ bias,
                const u16* __restrict__ pb, float* __restrict__ out) {
  const size_t base = ((size_t)blockIdx.x * 256 + threadIdx.x) * 4;
  const int col = (int)(base & 1023);
  float4 v = *(const float4*)(x2 + base);
  const float4 bb = *(const float4*)(bias + col);
  v.x += bb.x; v.y += bb.y; v.z += bb.z; v.w += bb.w;
#pragma unroll
  for (int z = 0; z < 4; z++) {
    const ushort4 p = *(const ushort4*)(pb + (size_t)z * 2097152 + base);
    v.x += bf2f(p.x); v.y += bf2f(p.y); v.z += bf2f(p.z); v.w += bf2f(p.w);
  }
  *(float4*)(out + base) = v;
}

// ---------------- LDS-free frag-packed bf16 GEMM, 128x128, split-K ----------
// (round-12 best config: depth-1 dbuf, launch_bounds(256,3))
// EPI 0: QKV split -> attn-packed Qp/Kp/Vp. Q is pre-scaled by log2(e)/8 so
// attn's softmax is a bare exp2 (removes 16 v_mul from its serial chain).
template <int EPI, int KS>
__global__ __launch_bounds__(256, 3)
void gemm_pk(const u16* __restrict__ Ap, const u16* __restrict__ Bp,
             int M, int N, int K,
             const float* __restrict__ bias, u16* __restrict__ pb,
             u16* __restrict__ outB,
             u16* __restrict__ qo, u16* __restrict__ ko, u16* __restrict__ vo) {
  const int t = threadIdx.x;
  const int l = t & 63;
  const int w = t >> 6;
  const int WR = (w >> 1) * 64, WC = (w & 1) * 64;
  const int l15 = l & 15, lg = l >> 4;

  // XCD-chunked swizzle (gridDim.x % 8 == 0 at all call sites)
  const int nx = gridDim.x;
  const u32 bid = blockIdx.y * nx + blockIdx.x;
  const int nxc = nx >> 3;
  const u32 r = bid >> 3;
  const int bx = (bid & 7) * nxc + (int)(r % (u32)nxc);
  const int by = (int)(r / (u32)nxc);

  const int m0 = by * 128, n0 = bx * 128;
  const int KT = K >> 5;               // total k-tiles
  const int nt = (K / KS) >> 5;        // k-tiles this z-slice
  const int t0 = blockIdx.z * nt;

  const u16* aB = Ap + ((size_t)((m0 + WR) >> 4) * KT + t0) * 512 + l * 8;
  const u16* bB = Bp + ((size_t)((n0 + WC) >> 4) * KT + t0) * 512 + l * 8;

  f32x4 acc[4][4] = {};
  bf16x8 a0[4], b0[4], a1[4], b1[4];

  auto LD = [&](bf16x8 (&af)[4], bf16x8 (&bf_)[4], int ti) {
#pragma unroll
    for (int i = 0; i < 4; i++)
      af[i] = *(const bf16x8*)(aB + ((size_t)i * KT + ti) * 512);
#pragma unroll
    for (int j = 0; j < 4; j++)
      bf_[j] = *(const bf16x8*)(bB + ((size_t)j * KT + ti) * 512);
  };
  auto FMA = [&](bf16x8 (&af)[4], bf16x8 (&bf_)[4]) {
    __builtin_amdgcn_s_setprio(1);
#pragma unroll
    for (int i = 0; i < 4; i++)
#pragma unroll
      for (int j = 0; j < 4; j++)
        acc[i][j] = mfma16(af[i], bf_[j], acc[i][j]);
    __builtin_amdgcn_s_setprio(0);
  };

  LD(a0, b0, 0);
  for (int ti = 0; ti < nt; ti += 2) {
    LD(a1, b1, (ti + 1 < nt) ? ti + 1 : ti);   // prefetch; clamped tail reload
    FMA(a0, b0);
    LD(a0, b0, (ti + 2 < nt) ? ti + 2 : ti);
    FMA(a1, b1);
  }

  const int mr0 = m0 + WR + lg * 4;
  const int nc0 = n0 + WC + l15;
#pragma unroll
  for (int i = 0; i < 4; i++) {
    const int mr = mr0 + i * 16;  // base row (multiple of 4); rows mr..mr+3
#pragma unroll
    for (int j = 0; j < 4; j++) {
      const int nc = nc0 + j * 16;
      if (EPI == 0) {
        const int sel = nc >> 10;
        const int d = nc & 1023;
        const int h = d >> 6, dl = d & 63;
        const int kt2 = mr >> 5;
        if (sel == 2) {
          // Vp[h][kt][nb][lane][el] (attn layout)
          const int lgp = (mr >> 3) & 3, el0 = mr & 7;
          const int nb = dl >> 4, l15p = dl & 15;
          u16* dst = vo + (size_t)(h * 64 + kt2) * 2048 + nb * 512 +
                     (lgp * 16 + l15p) * 8 + el0;
          ushort4 o;
          o.x = f2bf(acc[i][j][0]); o.y = f2bf(acc[i][j][1]);
          o.z = f2bf(acc[i][j][2]); o.w = f2bf(acc[i][j][3]);
          *(ushort4*)dst = o;
        } else {
          // Qp/Kp[h][kt][f][kk][lane][el] (attn layout)
          // Q pre-scaled by log2(e)/8: softmax becomes exp2(q'.k)
          const float qscale = (sel == 0) ? 0.1803368801f : 1.0f;
          const int f = (mr >> 4) & 1, l15p0 = mr & 15;
          const int kk = dl >> 5, lgp = (dl >> 3) & 3, el = dl & 7;
          u16* dst = (sel == 0 ? qo : ko) + (size_t)(h * 64 + kt2) * 2048 +
                     f * 1024 + kk * 512 + (lgp * 16 + l15p0) * 8 + el;
#pragma unroll
          for (int e = 0; e < 4; e++)
            dst[e * 8] = f2bf(acc[i][j][e] * qscale);
        }
      } else if (EPI == 2) {
        const float bb = bias[nc];
#pragma unroll
        for (int e = 0; e < 4; e++) {
          const float v = acc[i][j][e] + bb;
          const float g = 0.5f * v * (1.0f + tanhf(0.7978845608028654f * (v + 0.044715f * v * v * v)));
          outB[pk_addr(mr + e, nc, 4096)] = f2bf(g);
        }
      } else {
        u16* po = pb + (size_t)blockIdx.z * M * N;
#pragma unroll
        for (int e = 0; e < 4; e++)
          po[(size_t)(mr + e) * N + nc] = f2bf(acc[i][j][e]);
      }
    }
  }
}

// ---------------- causal flash attention v4c ---------------------------------
// Pre-scaled Q (exp2 direct) + uniform-branch causal mask: non-diagonal tiles
// (15 of 16 avg) skip all 16 per-element compares/cndmasks.
__device__ __forceinline__ void attn_load(
    bf16x8 (&kf)[2][2], bf16x8 (&vf)[4],
    const u16* __restrict__ Kp, const u16* __restrict__ Vp,
    int hkt, int l) {  // hkt = (h*64 + kt) * 2048
#pragma unroll
  for (int f = 0; f < 2; f++)
#pragma unroll
    for (int kk = 0; kk < 2; kk++)
      kf[kk][f] = *(const bf16x8*)(Kp + hkt + f * 1024 + kk * 512 + l * 8);
#pragma unroll
  for (int nb = 0; nb < 4; nb++)
    vf[nb] = *(const bf16x8*)(Vp + hkt + nb * 512 + l * 8);
}

__device__ __forceinline__ void attn_tile(
    const bf16x8 (&kf)[2][2], const bf16x8 (&vf)[4], const bf16x8 (&qf)[2][2],
    f32x4 (&accO)[2][4], float (&lsum)[2], u16* myP,
    int k0, bool diag, int qb, int l15, int lg) {
  f32x4 sv[2][2] = {};
  __builtin_amdgcn_s_setprio(1);
#pragma unroll
  for (int g = 0; g < 2; g++)
#pragma unroll
    for (int f = 0; f < 2; f++)
#pragma unroll
      for (int kk = 0; kk < 2; kk++)
        sv[g][f] = mfma16(kf[kk][f], qf[g][kk], sv[g][f]);
  __builtin_amdgcn_s_setprio(0);
  // sv[g][f][e] = scaled score(q = qb+g*16+l15, k = k0+f*16+lg*4+e)
  if (diag) {
#pragma unroll
    for (int g = 0; g < 2; g++) {
#pragma unroll
      for (int f = 0; f < 2; f++) {
        bf16x4 pk;
        float ps = 0.f;
#pragma unroll
        for (int e = 0; e < 4; e++) {
          float p = exp2f(sv[g][f][e]);
          if (k0 + f * 16 + lg * 4 + e > qb + g * 16 + l15) p = 0.f;
          ps += p;
          pk[e] = (bf16)p;
        }
        lsum[g] += ps;
        *(bf16x4*)(myP + g * 640 + l15 * 40 + f * 16 + lg * 4) = pk;
      }
    }
  } else {
#pragma unroll
    for (int g = 0; g < 2; g++) {
#pragma unroll
      for (int f = 0; f < 2; f++) {
        bf16x4 pk;
        float ps = 0.f;
#pragma unroll
        for (int e = 0; e < 4; e++) {
          const float p = exp2f(sv[g][f][e]);
          ps += p;
          pk[e] = (bf16)p;
        }
        lsum[g] += ps;
        *(bf16x4*)(myP + g * 640 + l15 * 40 + f * 16 + lg * 4) = pk;
      }
    }
  }
  const bf16x8 pf0 = *(const bf16x8*)(myP + l15 * 40 + lg * 8);
  const bf16x8 pf1 = *(const bf16x8*)(myP + 640 + l15 * 40 + lg * 8);
  __builtin_amdgcn_s_setprio(1);
#pragma unroll
  for (int nb = 0; nb < 4; nb++) {
    accO[0][nb] = mfma16(pf0, vf[nb], accO[0][nb]);
    accO[1][nb] = mfma16(pf1, vf[nb], accO[1][nb]);
  }
  __builtin_amdgcn_s_setprio(0);
}

__global__ __launch_bounds__(256)
void attn_fwd(const u16* __restrict__ Qp, const u16* __restrict__ Kp,
              const u16* __restrict__ Vp, u16* __restrict__ Ob) {
  __shared__ __attribute__((aligned(16))) char smem[33280];
  float* sO = (float*)smem;            // [4][2048] f32 (after barrier)
  float* sL = (float*)(smem + 32768);  // [4][32]
  u16* lP = (u16*)smem;                // [2 buf][4 waves][1280 u16]

  const int t = threadIdx.x;
  const int l = t & 63, w = t >> 6;
  const int l15 = l & 15, lg = l >> 4;
  const u32 bid = blockIdx.x;
  const u32 vb = (bid & 7) * 128 + (bid >> 3);
  const int h = (int)(vb >> 6);
  const int qt = 63 - (int)(vb & 63);  // LPT within chunk
  const int qb = qt * 32;

  u16* myPA = lP + w * 1280;
  u16* myPB = lP + 5120 + w * 1280;

  bf16x8 qf[2][2];
#pragma unroll
  for (int g = 0; g < 2; g++)
#pragma unroll
    for (int kk = 0; kk < 2; kk++)
      qf[g][kk] = *(const bf16x8*)(Qp + (size_t)(h * 64 + qt) * 2048 +
                                   g * 1024 + kk * 512 + l * 8);

  f32x4 accO[2][4] = {};
  float lsum[2] = {0.f, 0.f};

  if (w <= qt) {
    const int hb = h * 64;
    bf16x8 kfA[2][2], vfA[4], kfB[2][2], vfB[4];
    attn_load(kfA, vfA, Kp, Vp, (hb + w) * 2048, l);
    int kt = w;
    while (true) {
      const int ktB = kt + 4;
      const bool hasB = (ktB <= qt);
      attn_load(kfB, vfB, Kp, Vp, (hb + (hasB ? ktB : kt)) * 2048, l);
      attn_tile(kfA, vfA, qf, accO, lsum, myPA, kt * 32, kt == qt, qb, l15, lg);
      if (!hasB) break;
      const int ktA = kt + 8;
      const bool hasA = (ktA <= qt);
      attn_load(kfA, vfA, Kp, Vp, (hb + (hasA ? ktA : ktB)) * 2048, l);
      attn_tile(kfB, vfB, qf, accO, lsum, myPB, ktB * 32, ktB == qt, qb, l15, lg);
      if (!hasA) break;
      kt = ktA;
    }
  }

  float lsr[2];
#pragma unroll
  for (int g = 0; g < 2; g++) {
    float v = lsum[g];
    v += __shfl_xor(v, 16);
    v += __shfl_xor(v, 32);
    lsr[g] = v;
  }

  __syncthreads();  // all waves done with lP; smem becomes sO
#pragma unroll
  for (int g = 0; g < 2; g++) {
#pragma unroll
    for (int nb = 0; nb < 4; nb++)
#pragma unroll
      for (int e = 0; e < 4; e++)
        sO[w * 2048 + (g * 16 + lg * 4 + e) * 64 + nb * 16 + l15] = accO[g][nb][e];
    if (lg == 0) sL[w * 32 + g * 16 + l15] = lsr[g];
  }
  __syncthreads();

  const int base = t * 8;
  const int row = base >> 6;
  const int col = base & 63;
  f32x4 a0 = {}, a1 = {};
  float ls = 0.f;
#pragma unroll
  for (int ww = 0; ww < 4; ww++) {
    a0 += *(const f32x4*)&sO[ww * 2048 + base];
    a1 += *(const f32x4*)&sO[ww * 2048 + base + 4];
    ls += sL[ww * 32 + row];
  }
  const float rinv = 1.0f / ls;
  u16x8 o;
#pragma unroll
  for (int j = 0; j < 4; j++) {
    o[j] = f2bf(a0[j] * rinv);
    o[4 + j] = f2bf(a1[j] * rinv);
  }
  const int grow = qb + row;
  const int gcol = h * 64 + col;
  *(u16x8*)(Ob + pk_addr(grow, gcol, 1024)) = o;
}

// ---------------- launch ----------------------------------------------------
extern "C" void kernel_launch(void* const* d_in, const int* in_sizes, int n_in,
                              void* d_out, int out_size, void* d_ws, size_t ws_size,
                              hipStream_t stream) {
  const float* x     = (const float*)d_in[0];
  const float* W_qkv = (const float*)d_in[1];
  const float* W_o   = (const float*)d_in[2];
  const float* W1    = (const float*)d_in[3];
  const float* b1    = (const float*)d_in[4];
  const float* W2    = (const float*)d_in[5];
  const float* b2    = (const float*)d_in[6];
  const float* ln_aw = (const float*)d_in[7];
  const float* ln_ab = (const float*)d_in[8];
  const float* ln_mw = (const float*)d_in[9];
  const float* ln_mb = (const float*)d_in[10];

  // workspace (peak 71.3 MB):
  char* ws = (char*)d_ws;
  u16* Wqkv_t = (u16*)(ws);                  // pk [3072][1024]     6 MB persistent
  u16* Wo_t   = (u16*)(ws + 6291456);        // pk [1024][1024]     2 MB persistent
  u16* W1_t   = (u16*)(ws + 8388608);        // pk [4096][1024]     8 MB persistent
  u16* W2_t   = (u16*)(ws + 16777216);       // pk [1024][4096]     8 MB persistent
  u16* h1     = (u16*)(ws + 25165824);       // pk [2048][1024]     4 MB (h2 alias)
  u16* h2     = h1;
  u16* Qp     = (u16*)(ws + 29360128);       // attn-packed Q       4 MB
  u16* Kp     = (u16*)(ws + 33554432);       // attn-packed K       4 MB
  u16* Vp     = (u16*)(ws + 37748736);       // attn-packed V       4 MB
  u16* attnb  = (u16*)(ws + 41943040);       // pk [2048][1024]     4 MB
  u16* ffb    = (u16*)(ws + 29360128);       // pk [2048][4096]    16 MB aliases Qp..attnb
  u16* pb     = (u16*)(ws + 46137344);       // 4x bf16 [2048][1024] 16 MB partials
  float* x2   = (float*)(ws + 62914560);     // f32 [2048][1024]    8 MB
  (void)ws_size; (void)in_sizes; (void)n_in; (void)out_size;

  // weights conversion + first LN fused (independent work, one launch)
  prep_all<<<5120, 256, 0, stream>>>(W_qkv, W_o, W1, W2, x, ln_aw, ln_ab,
                                     Wqkv_t, Wo_t, W1_t, W2_t, h1);

  // QKV: M=2048 N=3072 K=1024 -> (24,16) = 384 blocks
  gemm_pk<0, 1><<<dim3(24, 16), 256, 0, stream>>>(
      h1, Wqkv_t, 2048, 3072, 1024, nullptr, nullptr, nullptr, Qp, Kp, Vp);

  attn_fwd<<<1024, 256, 0, stream>>>(Qp, Kp, Vp, attnb);

  // W_o: M=2048 N=1024 K=1024, split-K=4 -> (8,16,4) = 512 blocks
  gemm_pk<4, 4><<<dim3(8, 16, 4), 256, 0, stream>>>(
      attnb, Wo_t, 2048, 1024, 1024, nullptr, pb, nullptr, nullptr, nullptr, nullptr);

  reduce_ln<<<2048, 256, 0, stream>>>(x, pb, ln_mw, ln_mb, x2, h2);

  // FF1: M=2048 N=4096 K=1024 -> (32,16) = 512 blocks
  gemm_pk<2, 1><<<dim3(32, 16), 256, 0, stream>>>(
      h2, W1_t, 2048, 4096, 1024, b1, nullptr, ffb, nullptr, nullptr, nullptr);

  // FF2: M=2048 N=1024 K=4096, split-K=4 -> (8,16,4) = 512 blocks
  gemm_pk<4, 4><<<dim3(8, 16, 4), 256, 0, stream>>>(
      ffb, W2_t, 2048, 1024, 4096, nullptr, pb, nullptr, nullptr, nullptr, nullptr);

  reduce_out<<<2048, 256, 0, stream>>>(x2, b2, pb, (float*)d_out);
}